// Round 1
// baseline (76.050 us; speedup 1.0000x reference)
//
#include <hip/hip_runtime.h>

#define B_   1024
#define DIM_ 512
#define L_   512

// ---------------- Kernel A: qkv GEMM + in_proj, planar de-interleave -------
// C[b,o] = sum_k x[b,k] * w[o,k]   (w is [1536,512] row-major, o = 3*l + c)
// c==0 -> q_plane[b][l] = C*ipw0+ipb0
// c==1 -> kv_plane[b][2l]   = C*ipw1+ipb1   (k)
// c==2 -> kv_plane[b][2l+1] = C*ipw2+ipb2   (v)
__global__ __launch_bounds__(256) void qkv_gemm_kernel(
    const float* __restrict__ x, const float* __restrict__ w,
    const float* __restrict__ ipw, const float* __restrict__ ipb,
    float* __restrict__ qp, float* __restrict__ kvp)
{
  __shared__ float As[16][68];  // [k][row], +4 pad keeps float4 alignment
  __shared__ float Ws[16][68];  // [k][col]
  const int tid  = threadIdx.x;
  const int row0 = blockIdx.y * 64;
  const int col0 = blockIdx.x * 64;
  const int tx = tid & 15, ty = tid >> 4;
  const int lr = tid >> 2;          // 0..63: tile row loaded by this thread
  const int lk = (tid & 3) << 2;    // 0,4,8,12: k-chunk
  float acc[4][4] = {};
  const float* xg = &x[(size_t)(row0 + lr) * DIM_ + lk];
  const float* wg = &w[(size_t)(col0 + lr) * DIM_ + lk];

  for (int k0 = 0; k0 < DIM_; k0 += 16) {
    float4 av = *(const float4*)(xg + k0);
    float4 wv = *(const float4*)(wg + k0);
    __syncthreads();
    As[lk + 0][lr] = av.x; As[lk + 1][lr] = av.y;
    As[lk + 2][lr] = av.z; As[lk + 3][lr] = av.w;
    Ws[lk + 0][lr] = wv.x; Ws[lk + 1][lr] = wv.y;
    Ws[lk + 2][lr] = wv.z; Ws[lk + 3][lr] = wv.w;
    __syncthreads();
#pragma unroll
    for (int kk = 0; kk < 16; ++kk) {
      float4 a4 = *(const float4*)&As[kk][ty << 2];
      float4 b4 = *(const float4*)&Ws[kk][tx << 2];
      float a[4] = {a4.x, a4.y, a4.z, a4.w};
      float b[4] = {b4.x, b4.y, b4.z, b4.w};
#pragma unroll
      for (int i = 0; i < 4; ++i)
#pragma unroll
        for (int j = 0; j < 4; ++j)
          acc[i][j] = fmaf(a[i], b[j], acc[i][j]);
    }
  }

  const float pw0 = ipw[0], pw1 = ipw[1], pw2 = ipw[2];
  const float pb0 = ipb[0], pb1 = ipb[1], pb2 = ipb[2];
#pragma unroll
  for (int i = 0; i < 4; ++i) {
    const int br = row0 + (ty << 2) + i;
#pragma unroll
    for (int j = 0; j < 4; ++j) {
      const int o = col0 + (tx << 2) + j;
      const int l = o / 3;
      const int c = o - l * 3;
      const float v = acc[i][j];
      if (c == 0)      qp[(size_t)br * L_ + l]            = fmaf(v, pw0, pb0);
      else if (c == 1) kvp[(size_t)br * 2 * L_ + 2*l + 0] = fmaf(v, pw1, pb1);
      else             kvp[(size_t)br * 2 * L_ + 2*l + 1] = fmaf(v, pw2, pb2);
    }
  }
}

// ---------------- Kernel B: rank-1 attention + out_proj + residual ---------
// one block per batch b; 128 threads, 4 query rows each
__global__ __launch_bounds__(128) void attn_kernel(
    const float* __restrict__ qp, const float* __restrict__ kvp,
    const float* __restrict__ x, const float* __restrict__ ow,
    const float* __restrict__ ob, float* __restrict__ out)
{
  __shared__ float2 kv[L_];
  __shared__ float redmax[2], redmin[2];
  const int b = blockIdx.x, tid = threadIdx.x;
  const float2* __restrict__ kvg = (const float2*)&kvp[(size_t)b * 2 * L_];

  float kmax = -1e30f, kmin = 1e30f;
  for (int j = tid; j < L_; j += 128) {
    float2 t = kvg[j];
    kv[j] = t;
    kmax = fmaxf(kmax, t.x);
    kmin = fminf(kmin, t.x);
  }
#pragma unroll
  for (int off = 32; off; off >>= 1) {
    kmax = fmaxf(kmax, __shfl_xor(kmax, off));
    kmin = fminf(kmin, __shfl_xor(kmin, off));
  }
  if ((tid & 63) == 0) { redmax[tid >> 6] = kmax; redmin[tid >> 6] = kmin; }
  __syncthreads();
  kmax = fmaxf(redmax[0], redmax[1]);
  kmin = fminf(redmin[0], redmin[1]);

  const float L2E = 1.44269504f;
  float qs[4], m2[4], num[4] = {0,0,0,0}, den[4] = {0,0,0,0};
#pragma unroll
  for (int ii = 0; ii < 4; ++ii) {
    float q = qp[(size_t)b * L_ + ii * 128 + tid] * L2E;
    qs[ii] = q;
    m2[ii] = (q > 0.f) ? q * kmax : q * kmin;  // max_j of qs*k_j (exp2 domain)
  }

  // 2 (k,v) pairs per ds_read_b128
  for (int j2 = 0; j2 < L_ / 2; ++j2) {
    float4 t = *(const float4*)&kv[j2 * 2];
#pragma unroll
    for (int ii = 0; ii < 4; ++ii) {
      float e0 = __builtin_amdgcn_exp2f(fmaf(qs[ii], t.x, -m2[ii]));
      num[ii] = fmaf(e0, t.y, num[ii]);
      den[ii] += e0;
      float e1 = __builtin_amdgcn_exp2f(fmaf(qs[ii], t.z, -m2[ii]));
      num[ii] = fmaf(e1, t.w, num[ii]);
      den[ii] += e1;
    }
  }

  const float w0 = ow[0], b0 = ob[0];
#pragma unroll
  for (int ii = 0; ii < 4; ++ii) {
    const int i = ii * 128 + tid;
    out[(size_t)b * L_ + i] = fmaf(num[ii] / den[ii], w0, b0) + x[(size_t)b * L_ + i];
  }
}

extern "C" void kernel_launch(void* const* d_in, const int* in_sizes, int n_in,
                              void* d_out, int out_size, void* d_ws, size_t ws_size,
                              hipStream_t stream) {
  const float* x     = (const float*)d_in[0];
  const float* qkv_w = (const float*)d_in[1];
  const float* ipw   = (const float*)d_in[2];
  const float* ipb   = (const float*)d_in[3];
  const float* ow    = (const float*)d_in[4];
  const float* ob    = (const float*)d_in[5];
  float* out = (float*)d_out;

  float* qp  = (float*)d_ws;            // B*L floats   (2 MB)
  float* kvp = qp + (size_t)B_ * L_;    // B*L*2 floats (4 MB), interleaved k,v

  dim3 gA(24, 16), bA(256);
  qkv_gemm_kernel<<<gA, bA, 0, stream>>>(x, qkv_w, ipw, ipb, qp, kvp);

  attn_kernel<<<dim3(B_), dim3(128), 0, stream>>>(qp, kvp, x, ow, ob, out);
}

// Round 2
// 69.018 us; speedup vs baseline: 1.1019x; 1.1019x over previous
//
#include <hip/hip_runtime.h>

#define B_   1024
#define DIM_ 512
#define L_   512
#define NOUT 1536

typedef __attribute__((ext_vector_type(8))) short short8;
typedef __attribute__((ext_vector_type(4))) float f32x4;

__device__ __forceinline__ unsigned short f2bf(float f) {
  unsigned u = __float_as_uint(f);
  u += 0x7FFFu + ((u >> 16) & 1u);   // round-to-nearest-even
  return (unsigned short)(u >> 16);
}

// ---------------- Kernel 0: fp32 -> bf16 conversion of x and qkv_w ---------
__global__ __launch_bounds__(256) void cvt_kernel(
    const float* __restrict__ x, const float* __restrict__ w,
    unsigned short* __restrict__ xb, unsigned short* __restrict__ wb)
{
  const int nx4 = (B_ * DIM_) / 4;              // 131072 float4s in x
  const int nt4 = nx4 + (NOUT * DIM_) / 4;      // + 196608 in w
  int i = blockIdx.x * 256 + threadIdx.x;
  if (i >= nt4) return;
  float4 v;
  unsigned int* dst;
  if (i < nx4) { v = ((const float4*)x)[i];        dst = (unsigned int*)xb + 2 * i; }
  else { int j = i - nx4; v = ((const float4*)w)[j]; dst = (unsigned int*)wb + 2 * j; }
  unsigned int lo = (unsigned int)f2bf(v.x) | ((unsigned int)f2bf(v.y) << 16);
  unsigned int hi = (unsigned int)f2bf(v.z) | ((unsigned int)f2bf(v.w) << 16);
  dst[0] = lo; dst[1] = hi;
}

// ---------------- Kernel A: MFMA GEMM + in_proj, planar de-interleave ------
// C[b,o] = sum_k x[b,k]*w[o,k]; one wave per 32x32 output tile, no LDS —
// A (1MB) and B (1.5MB) bf16 are L2-resident, fragments loaded directly.
__global__ __launch_bounds__(64) void gemm_kernel(
    const unsigned short* __restrict__ A,   // [1024][512] bf16
    const unsigned short* __restrict__ Bw,  // [1536][512] bf16 (row-major [o][k])
    const float* __restrict__ ipw, const float* __restrict__ ipb,
    float* __restrict__ qp, float* __restrict__ kvp)
{
  const int lane = threadIdx.x;
  const int row0 = blockIdx.y * 32;
  const int col0 = blockIdx.x * 32;
  const int lm = lane & 15;
  const int kb = (lane >> 4) * 8;   // k sub-offset of this lane's fragment

  const unsigned short* a0p = A  + (size_t)(row0 + lm) * DIM_ + kb;
  const unsigned short* a1p = a0p + 16 * DIM_;
  const unsigned short* b0p = Bw + (size_t)(col0 + lm) * DIM_ + kb;
  const unsigned short* b1p = b0p + 16 * DIM_;

  f32x4 acc00 = {0.f,0.f,0.f,0.f}, acc01 = {0.f,0.f,0.f,0.f};
  f32x4 acc10 = {0.f,0.f,0.f,0.f}, acc11 = {0.f,0.f,0.f,0.f};

#pragma unroll 4
  for (int k0 = 0; k0 < DIM_; k0 += 32) {
    short8 a0 = *(const short8*)(a0p + k0);
    short8 a1 = *(const short8*)(a1p + k0);
    short8 b0 = *(const short8*)(b0p + k0);
    short8 b1 = *(const short8*)(b1p + k0);
    acc00 = __builtin_amdgcn_mfma_f32_16x16x32_bf16(a0, b0, acc00, 0, 0, 0);
    acc01 = __builtin_amdgcn_mfma_f32_16x16x32_bf16(a0, b1, acc01, 0, 0, 0);
    acc10 = __builtin_amdgcn_mfma_f32_16x16x32_bf16(a1, b0, acc10, 0, 0, 0);
    acc11 = __builtin_amdgcn_mfma_f32_16x16x32_bf16(a1, b1, acc11, 0, 0, 0);
  }

  const float pw0 = ipw[0], pw1 = ipw[1], pw2 = ipw[2];
  const float pb0 = ipb[0], pb1 = ipb[1], pb2 = ipb[2];
  const int crow = (lane >> 4) * 2;  // *4 regs, but regs iterate below; row base = (lane>>4)*4
  (void)crow;

  // C/D layout: col = lane&15, row = (lane>>4)*4 + reg
  f32x4 accs[2][2] = {{acc00, acc01}, {acc10, acc11}};
#pragma unroll
  for (int cj = 0; cj < 2; ++cj) {
    const int o = col0 + cj * 16 + lm;
    const int l = o / 3;
    const int c = o - 3 * l;
    const float pw = (c == 0) ? pw0 : ((c == 1) ? pw1 : pw2);
    const float pb = (c == 0) ? pb0 : ((c == 1) ? pb1 : pb2);
#pragma unroll
    for (int ri = 0; ri < 2; ++ri) {
#pragma unroll
      for (int r = 0; r < 4; ++r) {
        const int row = row0 + ri * 16 + (lane >> 4) * 4 + r;
        const float v = fmaf(accs[ri][cj][r], pw, pb);
        if (c == 0)      qp[(size_t)row * L_ + l] = v;
        else             kvp[(size_t)row * 2 * L_ + 2 * l + (c - 1)] = v;
      }
    }
  }
}

// ---------------- Kernel B: rank-1 attention + out_proj + residual ---------
// one block per batch; (k,v) reads are block-uniform -> scalar loads (SMEM),
// no LDS, no max-subtraction (scores bounded far below fp32 exp overflow).
__global__ __launch_bounds__(256) void attn_kernel(
    const float* __restrict__ qp, const float* __restrict__ kvp,
    const float* __restrict__ x, const float* __restrict__ ow,
    const float* __restrict__ ob, float* __restrict__ out)
{
  const int b = blockIdx.x, tid = threadIdx.x;
  const float* __restrict__ kv = kvp + (size_t)b * 2 * L_;
  const float L2E = 1.44269504f;
  float q0 = qp[(size_t)b * L_ + tid] * L2E;
  float q1 = qp[(size_t)b * L_ + 256 + tid] * L2E;
  float n0 = 0.f, d0 = 0.f, n1 = 0.f, d1 = 0.f;

#pragma unroll 4
  for (int j = 0; j < L_; j += 2) {
    float4 p = *(const float4*)(kv + 2 * j);   // k[j],v[j],k[j+1],v[j+1] (uniform)
    float e;
    e = __builtin_amdgcn_exp2f(q0 * p.x); d0 += e; n0 = fmaf(e, p.y, n0);
    e = __builtin_amdgcn_exp2f(q0 * p.z); d0 += e; n0 = fmaf(e, p.w, n0);
    e = __builtin_amdgcn_exp2f(q1 * p.x); d1 += e; n1 = fmaf(e, p.y, n1);
    e = __builtin_amdgcn_exp2f(q1 * p.z); d1 += e; n1 = fmaf(e, p.w, n1);
  }

  const float w0 = ow[0], b0 = ob[0];
  out[(size_t)b * L_ + tid]       = fmaf(n0 / d0, w0, b0) + x[(size_t)b * L_ + tid];
  out[(size_t)b * L_ + 256 + tid] = fmaf(n1 / d1, w0, b0) + x[(size_t)b * L_ + 256 + tid];
}

extern "C" void kernel_launch(void* const* d_in, const int* in_sizes, int n_in,
                              void* d_out, int out_size, void* d_ws, size_t ws_size,
                              hipStream_t stream) {
  const float* x     = (const float*)d_in[0];
  const float* qkv_w = (const float*)d_in[1];
  const float* ipw   = (const float*)d_in[2];
  const float* ipb   = (const float*)d_in[3];
  const float* ow    = (const float*)d_in[4];
  const float* ob    = (const float*)d_in[5];
  float* out = (float*)d_out;

  char* ws = (char*)d_ws;
  unsigned short* xb  = (unsigned short*)(ws);                 // 1.0 MB
  unsigned short* wb  = (unsigned short*)(ws + 1048576);       // 1.5 MB
  float*          qp  = (float*)(ws + 2621440);                // 2.0 MB
  float*          kvp = (float*)(ws + 4718592);                // 4.0 MB  (total 8.5 MB)

  cvt_kernel<<<dim3(1280), dim3(256), 0, stream>>>(x, qkv_w, xb, wb);

  dim3 gA(NOUT / 32, B_ / 32);   // 48 x 32 = 1536 waves
  gemm_kernel<<<gA, dim3(64), 0, stream>>>(xb, wb, ipw, ipb, qp, kvp);

  attn_kernel<<<dim3(B_), dim3(256), 0, stream>>>(qp, kvp, x, ow, ob, out);
}

// Round 3
// 37.170 us; speedup vs baseline: 2.0460x; 1.8568x over previous
//
#include <hip/hip_runtime.h>

#define B_   1024
#define DIM_ 512
#define L_   512
#define NOUT 1536
#define G_   128   // interpolation grid points per batch

typedef __attribute__((ext_vector_type(8))) short short8;
typedef __attribute__((ext_vector_type(4))) float f32x4;

__device__ __forceinline__ unsigned short f2bf(float f) {
  unsigned u = __float_as_uint(f);
  u += 0x7FFFu + ((u >> 16) & 1u);   // round-to-nearest-even
  return (unsigned short)(u >> 16);
}

// ---------------- Kernel 0: fp32 -> bf16 conversion of x and qkv_w ---------
__global__ __launch_bounds__(256) void cvt_kernel(
    const float* __restrict__ x, const float* __restrict__ w,
    unsigned short* __restrict__ xb, unsigned short* __restrict__ wb)
{
  const int nx4 = (B_ * DIM_) / 4;
  const int nt4 = nx4 + (NOUT * DIM_) / 4;
  int i = blockIdx.x * 256 + threadIdx.x;
  if (i >= nt4) return;
  float4 v;
  unsigned int* dst;
  if (i < nx4) { v = ((const float4*)x)[i];        dst = (unsigned int*)xb + 2 * i; }
  else { int j = i - nx4; v = ((const float4*)w)[j]; dst = (unsigned int*)wb + 2 * j; }
  dst[0] = (unsigned int)f2bf(v.x) | ((unsigned int)f2bf(v.y) << 16);
  dst[1] = (unsigned int)f2bf(v.z) | ((unsigned int)f2bf(v.w) << 16);
}

// ---------------- Kernel A: MFMA GEMM, K split across 4 waves --------------
// block = 256 thr (4 waves); wave w covers k in [w*128, w*128+128);
// 32x32 output tile per block; LDS reduction; in_proj fused in epilogue.
__global__ __launch_bounds__(256) void gemm_kernel(
    const unsigned short* __restrict__ A,   // [1024][512] bf16
    const unsigned short* __restrict__ Bw,  // [1536][512] bf16
    const float* __restrict__ ipw, const float* __restrict__ ipb,
    float* __restrict__ qp, float* __restrict__ kvp)
{
  __shared__ f32x4 part[4][2][2][64];   // 16 KB
  const int tid  = threadIdx.x;
  const int lane = tid & 63;
  const int w    = tid >> 6;
  const int row0 = blockIdx.y * 32;
  const int col0 = blockIdx.x * 32;
  const int lm = lane & 15;
  const int kb = (lane >> 4) * 8;
  const int kw = w * 128;

  const unsigned short* a0p = A  + (size_t)(row0 + lm) * DIM_ + kw + kb;
  const unsigned short* a1p = a0p + 16 * DIM_;
  const unsigned short* b0p = Bw + (size_t)(col0 + lm) * DIM_ + kw + kb;
  const unsigned short* b1p = b0p + 16 * DIM_;

  f32x4 acc00 = {0,0,0,0}, acc01 = {0,0,0,0}, acc10 = {0,0,0,0}, acc11 = {0,0,0,0};
#pragma unroll
  for (int k0 = 0; k0 < 128; k0 += 32) {
    short8 a0 = *(const short8*)(a0p + k0);
    short8 a1 = *(const short8*)(a1p + k0);
    short8 b0 = *(const short8*)(b0p + k0);
    short8 b1 = *(const short8*)(b1p + k0);
    acc00 = __builtin_amdgcn_mfma_f32_16x16x32_bf16(a0, b0, acc00, 0, 0, 0);
    acc01 = __builtin_amdgcn_mfma_f32_16x16x32_bf16(a0, b1, acc01, 0, 0, 0);
    acc10 = __builtin_amdgcn_mfma_f32_16x16x32_bf16(a1, b0, acc10, 0, 0, 0);
    acc11 = __builtin_amdgcn_mfma_f32_16x16x32_bf16(a1, b1, acc11, 0, 0, 0);
  }
  part[w][0][0][lane] = acc00;
  part[w][0][1][lane] = acc01;
  part[w][1][0][lane] = acc10;
  part[w][1][1][lane] = acc11;
  __syncthreads();

  const int ri = w >> 1, cj = w & 1;
  f32x4 s = part[0][ri][cj][lane] + part[1][ri][cj][lane]
          + part[2][ri][cj][lane] + part[3][ri][cj][lane];

  const float pw0 = ipw[0], pw1 = ipw[1], pw2 = ipw[2];
  const float pb0 = ipb[0], pb1 = ipb[1], pb2 = ipb[2];
  const int o = col0 + cj * 16 + lm;
  const int l = o / 3;
  const int c = o - 3 * l;
  const float pw = (c == 0) ? pw0 : ((c == 1) ? pw1 : pw2);
  const float pb = (c == 0) ? pb0 : ((c == 1) ? pb1 : pb2);
#pragma unroll
  for (int r = 0; r < 4; ++r) {
    const int row = row0 + ri * 16 + (lane >> 4) * 4 + r;
    const float v = fmaf(s[r], pw, pb);
    if (c == 0) qp[(size_t)row * L_ + l] = v;
    else        kvp[(size_t)row * 2 * L_ + 2 * l + (c - 1)] = v;
  }
}

// ---------------- Kernel B: rank-1 attention via per-batch interpolation ---
// f(q) = sum_j exp(q k_j) v_j / sum_j exp(q k_j): evaluate on G_-point grid
// over [qmin,qmax], Catmull-Rom interpolate the 512 rows. One block per batch.
__global__ __launch_bounds__(256) void attn_kernel(
    const float* __restrict__ qp, const float* __restrict__ kvp,
    const float* __restrict__ x, const float* __restrict__ ow,
    const float* __restrict__ ob, float* __restrict__ out)
{
  __shared__ float2 kvs[L_];      // 4 KB
  __shared__ float2 part2[256];   // 2 KB
  __shared__ float  fgrid[G_];
  __shared__ float  red[8];
  const int b = blockIdx.x, tid = threadIdx.x;
  const float2* __restrict__ kvg = (const float2*)&kvp[(size_t)b * 2 * L_];

  float q0 = qp[(size_t)b * L_ + tid];
  float q1 = qp[(size_t)b * L_ + 256 + tid];
  float2 t0 = kvg[tid], t1 = kvg[tid + 256];
  kvs[tid] = t0; kvs[tid + 256] = t1;

  float qmn = fminf(q0, q1), qmx = fmaxf(q0, q1);
#pragma unroll
  for (int off = 32; off; off >>= 1) {
    qmn = fminf(qmn, __shfl_xor(qmn, off));
    qmx = fmaxf(qmx, __shfl_xor(qmx, off));
  }
  if ((tid & 63) == 0) { red[tid >> 6] = qmn; red[4 + (tid >> 6)] = qmx; }
  __syncthreads();
  qmn = fminf(fminf(red[0], red[1]), fminf(red[2], red[3]));
  qmx = fmaxf(fmaxf(red[4], red[5]), fmaxf(red[6], red[7]));

  const float L2E = 1.44269504f;
  const float range = qmx - qmn;
  const float hstep = range * (1.f / (G_ - 1));
  const int g = tid & (G_ - 1);        // grid point
  const int h = tid >> 7;              // j-half
  const float gq = (qmn + hstep * (float)g) * L2E;
  float num = 0.f, den = 0.f;
  const float4* kv4 = (const float4*)&kvs[h * 256];
#pragma unroll 4
  for (int j = 0; j < 128; ++j) {
    float4 p = kv4[j];                 // k,v,k,v (wave-uniform broadcast)
    float e0 = __builtin_amdgcn_exp2f(gq * p.x);
    den += e0; num = fmaf(e0, p.y, num);
    float e1 = __builtin_amdgcn_exp2f(gq * p.z);
    den += e1; num = fmaf(e1, p.w, num);
  }
  part2[tid] = make_float2(num, den);
  __syncthreads();
  if (tid < G_) {
    float2 a = part2[tid], c = part2[tid + G_];
    fgrid[tid] = (a.x + c.x) / (a.y + c.y);
  }
  __syncthreads();

  const float inv_h = (range > 1e-20f) ? (float)(G_ - 1) / range : 0.f;
  const float w0 = ow[0], b0 = ob[0];
#pragma unroll
  for (int ii = 0; ii < 2; ++ii) {
    const float q = ii ? q1 : q0;
    float u = (q - qmn) * inv_h;
    u = fminf(fmaxf(u, 0.f), (float)(G_ - 1));
    int gi = (int)u;
    gi = min(gi, G_ - 2);
    const float t = u - (float)gi;
    const float p0 = fgrid[max(gi - 1, 0)];
    const float p1 = fgrid[gi];
    const float p2 = fgrid[gi + 1];
    const float p3 = fgrid[min(gi + 2, G_ - 1)];
    // Catmull-Rom
    const float f = 0.5f * (2.f * p1 + t * ((p2 - p0)
                  + t * ((2.f * p0 - 5.f * p1 + 4.f * p2 - p3)
                  + t * (3.f * (p1 - p2) + p3 - p0))));
    const int i = ii * 256 + tid;
    out[(size_t)b * L_ + i] = fmaf(f, w0, b0) + x[(size_t)b * L_ + i];
  }
}

extern "C" void kernel_launch(void* const* d_in, const int* in_sizes, int n_in,
                              void* d_out, int out_size, void* d_ws, size_t ws_size,
                              hipStream_t stream) {
  const float* x     = (const float*)d_in[0];
  const float* qkv_w = (const float*)d_in[1];
  const float* ipw   = (const float*)d_in[2];
  const float* ipb   = (const float*)d_in[3];
  const float* ow    = (const float*)d_in[4];
  const float* ob    = (const float*)d_in[5];
  float* out = (float*)d_out;

  char* ws = (char*)d_ws;
  unsigned short* xb  = (unsigned short*)(ws);                 // 1.0 MB
  unsigned short* wb  = (unsigned short*)(ws + 1048576);       // 1.5 MB
  float*          qp  = (float*)(ws + 2621440);                // 2.0 MB
  float*          kvp = (float*)(ws + 4718592);                // 4.0 MB

  cvt_kernel<<<dim3(1280), dim3(256), 0, stream>>>(x, qkv_w, xb, wb);

  dim3 gA(NOUT / 32, B_ / 32);
  gemm_kernel<<<gA, dim3(256), 0, stream>>>(xb, wb, ipw, ipb, qp, kvp);

  attn_kernel<<<dim3(B_), dim3(256), 0, stream>>>(qp, kvp, x, ow, ob, out);
}

// Round 4
// 30.260 us; speedup vs baseline: 2.5132x; 1.2283x over previous
//
#include <hip/hip_runtime.h>

#define B_   1024
#define DIM_ 512
#define L_   512
#define NOUT 1536
#define G_   128   // interpolation grid points per batch
#define LDA  40    // LDS row stride in ushorts (80 B): 2-way-max bank aliasing

typedef __attribute__((ext_vector_type(8))) short short8;
typedef __attribute__((ext_vector_type(4))) float f32x4;

__device__ __forceinline__ unsigned short f2bf(float f) {
  unsigned u = __float_as_uint(f);
  u += 0x7FFFu + ((u >> 16) & 1u);   // round-to-nearest-even
  return (unsigned short)(u >> 16);
}

// ---------------- Kernel A: fused cvt + MFMA GEMM + in_proj ----------------
// C[b,o] = sum_k x[b,k]*w[o,k]. 64x64 tile/block, BK=32, 4 waves each owning
// a 32x32 quadrant. fp32 loaded from global, converted to bf16 during LDS
// staging (no separate cvt kernel). Next tile's loads issued before compute.
__global__ __launch_bounds__(256) void gemm_kernel(
    const float* __restrict__ x, const float* __restrict__ w,
    const float* __restrict__ ipw, const float* __restrict__ ipb,
    float* __restrict__ qp, float* __restrict__ kvp)
{
  __shared__ unsigned short lds[2 * 64 * LDA];   // A tile then B tile, 10 KB
  unsigned short* aT = lds;
  unsigned short* bT = lds + 64 * LDA;

  const int tid  = threadIdx.x;
  const int lane = tid & 63;
  const int wv   = tid >> 6;
  const int row0 = blockIdx.y * 64;
  const int col0 = blockIdx.x * 64;

  // staging assignment: row sr (0..63), k-chunk sc (0,8,16,24)
  const int sr = tid >> 2;
  const int sc = (tid & 3) * 8;
  const float* xg = &x[(size_t)(row0 + sr) * DIM_ + sc];
  const float* wg = &w[(size_t)(col0 + sr) * DIM_ + sc];

  // fragment read assignment
  const int wr = wv >> 1, wc = wv & 1;
  const int lm = lane & 15;
  const int kq = (lane >> 4) * 8;                 // ushort offset within row
  const unsigned short* a0p = &aT[(wr * 32 + lm) * LDA + kq];
  const unsigned short* a1p = a0p + 16 * LDA;
  const unsigned short* b0p = &bT[(wc * 32 + lm) * LDA + kq];
  const unsigned short* b1p = b0p + 16 * LDA;

  f32x4 acc00 = {0,0,0,0}, acc01 = {0,0,0,0}, acc10 = {0,0,0,0}, acc11 = {0,0,0,0};

  // prologue: stage k0 = 0
  float4 al = *(const float4*)(xg);
  float4 ah = *(const float4*)(xg + 4);
  float4 bl = *(const float4*)(wg);
  float4 bh = *(const float4*)(wg + 4);
  {
    short8 av, bv;
    av[0]=f2bf(al.x); av[1]=f2bf(al.y); av[2]=f2bf(al.z); av[3]=f2bf(al.w);
    av[4]=f2bf(ah.x); av[5]=f2bf(ah.y); av[6]=f2bf(ah.z); av[7]=f2bf(ah.w);
    bv[0]=f2bf(bl.x); bv[1]=f2bf(bl.y); bv[2]=f2bf(bl.z); bv[3]=f2bf(bl.w);
    bv[4]=f2bf(bh.x); bv[5]=f2bf(bh.y); bv[6]=f2bf(bh.z); bv[7]=f2bf(bh.w);
    *(short8*)&aT[sr * LDA + sc] = av;
    *(short8*)&bT[sr * LDA + sc] = bv;
  }
  __syncthreads();

  for (int k0 = 32; k0 <= DIM_; k0 += 32) {
    if (k0 < DIM_) {   // issue next tile's loads early — latency hides under MFMA
      al = *(const float4*)(xg + k0);
      ah = *(const float4*)(xg + k0 + 4);
      bl = *(const float4*)(wg + k0);
      bh = *(const float4*)(wg + k0 + 4);
    }
    short8 a0 = *(const short8*)a0p;
    short8 a1 = *(const short8*)a1p;
    short8 b0 = *(const short8*)b0p;
    short8 b1 = *(const short8*)b1p;
    acc00 = __builtin_amdgcn_mfma_f32_16x16x32_bf16(a0, b0, acc00, 0, 0, 0);
    acc01 = __builtin_amdgcn_mfma_f32_16x16x32_bf16(a0, b1, acc01, 0, 0, 0);
    acc10 = __builtin_amdgcn_mfma_f32_16x16x32_bf16(a1, b0, acc10, 0, 0, 0);
    acc11 = __builtin_amdgcn_mfma_f32_16x16x32_bf16(a1, b1, acc11, 0, 0, 0);
    if (k0 < DIM_) {
      __syncthreads();   // all ds_reads of current tile done
      short8 av, bv;
      av[0]=f2bf(al.x); av[1]=f2bf(al.y); av[2]=f2bf(al.z); av[3]=f2bf(al.w);
      av[4]=f2bf(ah.x); av[5]=f2bf(ah.y); av[6]=f2bf(ah.z); av[7]=f2bf(ah.w);
      bv[0]=f2bf(bl.x); bv[1]=f2bf(bl.y); bv[2]=f2bf(bl.z); bv[3]=f2bf(bl.w);
      bv[4]=f2bf(bh.x); bv[5]=f2bf(bh.y); bv[6]=f2bf(bh.z); bv[7]=f2bf(bh.w);
      *(short8*)&aT[sr * LDA + sc] = av;
      *(short8*)&bT[sr * LDA + sc] = bv;
      __syncthreads();
    }
  }

  const float pw0 = ipw[0], pw1 = ipw[1], pw2 = ipw[2];
  const float pb0 = ipb[0], pb1 = ipb[1], pb2 = ipb[2];
  f32x4 accs[2][2] = {{acc00, acc01}, {acc10, acc11}};
#pragma unroll
  for (int cj = 0; cj < 2; ++cj) {
    const int o = col0 + wc * 32 + cj * 16 + lm;
    const int l = o / 3;
    const int c = o - 3 * l;
    const float pw = (c == 0) ? pw0 : ((c == 1) ? pw1 : pw2);
    const float pb = (c == 0) ? pb0 : ((c == 1) ? pb1 : pb2);
#pragma unroll
    for (int ri = 0; ri < 2; ++ri) {
#pragma unroll
      for (int r = 0; r < 4; ++r) {
        const int row = row0 + wr * 32 + ri * 16 + (lane >> 4) * 4 + r;
        const float v = fmaf(accs[ri][cj][r], pw, pb);
        if (c == 0) qp[(size_t)row * L_ + l] = v;
        else        kvp[(size_t)row * 2 * L_ + 2 * l + (c - 1)] = v;
      }
    }
  }
}

// ---------------- Kernel B: rank-1 attention via per-batch interpolation ---
// f(q) = sum_j exp(q k_j) v_j / sum_j exp(q k_j): evaluate on G_-point grid
// over [qmin,qmax], Catmull-Rom interpolate the 512 rows. One block per batch.
__global__ __launch_bounds__(256) void attn_kernel(
    const float* __restrict__ qp, const float* __restrict__ kvp,
    const float* __restrict__ x, const float* __restrict__ ow,
    const float* __restrict__ ob, float* __restrict__ out)
{
  __shared__ float2 kvs[L_];      // 4 KB
  __shared__ float2 part2[256];   // 2 KB
  __shared__ float  fgrid[G_];
  __shared__ float  red[8];
  const int b = blockIdx.x, tid = threadIdx.x;
  const float2* __restrict__ kvg = (const float2*)&kvp[(size_t)b * 2 * L_];

  float q0 = qp[(size_t)b * L_ + tid];
  float q1 = qp[(size_t)b * L_ + 256 + tid];
  float2 t0 = kvg[tid], t1 = kvg[tid + 256];
  kvs[tid] = t0; kvs[tid + 256] = t1;

  float qmn = fminf(q0, q1), qmx = fmaxf(q0, q1);
#pragma unroll
  for (int off = 32; off; off >>= 1) {
    qmn = fminf(qmn, __shfl_xor(qmn, off));
    qmx = fmaxf(qmx, __shfl_xor(qmx, off));
  }
  if ((tid & 63) == 0) { red[tid >> 6] = qmn; red[4 + (tid >> 6)] = qmx; }
  __syncthreads();
  qmn = fminf(fminf(red[0], red[1]), fminf(red[2], red[3]));
  qmx = fmaxf(fmaxf(red[4], red[5]), fmaxf(red[6], red[7]));

  const float L2E = 1.44269504f;
  const float range = qmx - qmn;
  const float hstep = range * (1.f / (G_ - 1));
  const int g = tid & (G_ - 1);        // grid point
  const int h = tid >> 7;              // j-half
  const float gq = (qmn + hstep * (float)g) * L2E;
  float num = 0.f, den = 0.f;
  const float4* kv4 = (const float4*)&kvs[h * 256];
#pragma unroll 4
  for (int j = 0; j < 128; ++j) {
    float4 p = kv4[j];                 // k,v,k,v (wave-uniform broadcast)
    float e0 = __builtin_amdgcn_exp2f(gq * p.x);
    den += e0; num = fmaf(e0, p.y, num);
    float e1 = __builtin_amdgcn_exp2f(gq * p.z);
    den += e1; num = fmaf(e1, p.w, num);
  }
  part2[tid] = make_float2(num, den);
  __syncthreads();
  if (tid < G_) {
    float2 a = part2[tid], c = part2[tid + G_];
    fgrid[tid] = (a.x + c.x) / (a.y + c.y);
  }
  __syncthreads();

  const float inv_h = (range > 1e-20f) ? (float)(G_ - 1) / range : 0.f;
  const float w0 = ow[0], b0 = ob[0];
#pragma unroll
  for (int ii = 0; ii < 2; ++ii) {
    const float q = ii ? q1 : q0;
    float u = (q - qmn) * inv_h;
    u = fminf(fmaxf(u, 0.f), (float)(G_ - 1));
    int gi = (int)u;
    gi = min(gi, G_ - 2);
    const float t = u - (float)gi;
    const float p0 = fgrid[max(gi - 1, 0)];
    const float p1 = fgrid[gi];
    const float p2 = fgrid[gi + 1];
    const float p3 = fgrid[min(gi + 2, G_ - 1)];
    // Catmull-Rom
    const float f = 0.5f * (2.f * p1 + t * ((p2 - p0)
                  + t * ((2.f * p0 - 5.f * p1 + 4.f * p2 - p3)
                  + t * (3.f * (p1 - p2) + p3 - p0))));
    const int i = ii * 256 + tid;
    out[(size_t)b * L_ + i] = fmaf(f, w0, b0) + x[(size_t)b * L_ + i];
  }
}

extern "C" void kernel_launch(void* const* d_in, const int* in_sizes, int n_in,
                              void* d_out, int out_size, void* d_ws, size_t ws_size,
                              hipStream_t stream) {
  const float* x     = (const float*)d_in[0];
  const float* qkv_w = (const float*)d_in[1];
  const float* ipw   = (const float*)d_in[2];
  const float* ipb   = (const float*)d_in[3];
  const float* ow    = (const float*)d_in[4];
  const float* ob    = (const float*)d_in[5];
  float* out = (float*)d_out;

  char* ws = (char*)d_ws;
  float* qp  = (float*)(ws);            // 2.0 MB
  float* kvp = (float*)(ws + 2097152);  // 4.0 MB

  dim3 gA(NOUT / 64, B_ / 64);          // 24 x 16 blocks
  gemm_kernel<<<gA, dim3(256), 0, stream>>>(x, qkv_w, ipw, ipb, qp, kvp);

  attn_kernel<<<dim3(B_), dim3(256), 0, stream>>>(qp, kvp, x, ow, ob, out);
}